// Round 4
// baseline (75.078 us; speedup 1.0000x reference)
//
#include <hip/hip_runtime.h>
#include <hip/hip_bf16.h>

#define BT 128   // B*T
#define NN 256   // nodes
#define FF 128   // features
#define HH 4     // heads
#define DD 32    // head dim
#define XK 136   // LDS stride (bf16) for xc / wt: 272B, 16B-aligned, spreads banks
#define WCS 264  // LDS col-stride (bf16) for whc: 528B
#define L2E 1.4426950408889634f

typedef __attribute__((ext_vector_type(8))) short bf16x8;
typedef __attribute__((ext_vector_type(4))) float f32x4;
typedef unsigned int uint;
typedef unsigned short ushort;

__device__ __forceinline__ float elu1(float x) { return x > 0.f ? x : (__expf(x) - 1.f); }
__device__ __forceinline__ float exp2_fast(float x) {
  float r; asm("v_exp_f32 %0, %1" : "=v"(r) : "v"(x)); return r;
}
__device__ __forceinline__ ushort f2bfn(float f) {
  __hip_bfloat16 h = __float2bfloat16(f);
  return *reinterpret_cast<ushort*>(&h);
}
__device__ __forceinline__ float bf2f(ushort u) {
  union { uint u; float f; } v; v.u = ((uint)u) << 16; return v.f;
}
__device__ __forceinline__ uint pk2(float a, float b) {  // -> v_cvt_pk_bf16_f32
  return (uint)f2bfn(a) | ((uint)f2bfn(b) << 16);
}

// One block per bt slice: compaction once, 2 layers x 4 heads of
// (GEMM -> scores -> PV -> residual+ELU), then LN+scatter. All intermediates
// LDS-resident; xnew round-trips through L2-resident bf16 scratch per layer.
__global__ __launch_bounds__(256) void fused_gnn(
    const float* __restrict__ xin, const int* __restrict__ mask,
    const float* __restrict__ W0, const float* __restrict__ a0,
    const float* __restrict__ W1, const float* __restrict__ a1,
    const float* __restrict__ gam, const float* __restrict__ bet,
    ushort* __restrict__ xg0, ushort* __restrict__ xg1,
    float* __restrict__ out) {
  __shared__ __align__(16) ushort xc[NN * XK];    // 69.6 KB compact x (bf16)
  __shared__ __align__(16) ushort wt[DD * XK];    // 8.7 KB  W head-slice^T
  __shared__ __align__(16) ushort whc[DD * WCS];  // 16.9 KB Whh^T compact
  __shared__ __align__(16) float s1s[NN];
  __shared__ __align__(16) float s2c[NN];
  __shared__ int jmap[NN];
  __shared__ int rrank[NN];
  __shared__ float redm[4];
  __shared__ int wcnt[4];

  const int bt = blockIdx.x;
  const int tid = threadIdx.x;
  const int lane = tid & 63;
  const int w = tid >> 6;
  const int la = lane & 15, lg = lane >> 4;

  // ---- phase A: ballot -> rank/jmap (mask is layer/head-invariant) ----
  const int mv = mask[bt * NN + tid] > 0;
  unsigned long long bal = __ballot(mv);
  if (lane == 0) wcnt[w] = __popcll(bal);
  __syncthreads();
  int base = 0;
  #pragma unroll
  for (int ww = 0; ww < 4; ++ww) if (ww < w) base += wcnt[ww];
  const int jv = wcnt[0] + wcnt[1] + wcnt[2] + wcnt[3];
  int rk = -1;
  if (mv) { rk = base + __popcll(bal & ((1ull << lane) - 1ull)); jmap[rk] = tid; }
  rrank[tid] = rk;
  __syncthreads();
  const int jv16 = (jv + 15) & ~15;
  const int nrt = jv16 >> 4;         // 16-row tiles of compact rows
  const int jvp64 = (jv16 + 63) & ~63;  // PV j-loop bound

  // stage xc (gathered, fp32->bf16), zero pad rows [jv, jv16)
  {
    const int r0 = tid >> 4;
    const int c0 = (tid & 15) * 8;
    #pragma unroll
    for (int it = 0; it < 16; ++it) {
      int r = r0 + it * 16;
      if (r < jv) {
        const float* xp = xin + ((size_t)bt * NN + jmap[r]) * FF + c0;
        float4 v0 = *(const float4*)xp;
        float4 v1 = *(const float4*)(xp + 4);
        uint4 q;
        q.x = pk2(v0.x, v0.y); q.y = pk2(v0.z, v0.w);
        q.z = pk2(v1.x, v1.y); q.w = pk2(v1.z, v1.w);
        *(uint4*)&xc[r * XK + c0] = q;
      } else if (r < jv16) {
        uint4 z = {0, 0, 0, 0};
        *(uint4*)&xc[r * XK + c0] = z;
      }
    }
  }
  // zero whc pad cols [jv16, jvp64) once (guards NaN bit-patterns; GEMM never writes them)
  if (tid >= jv16 && tid < jvp64) {
    #pragma unroll
    for (int d = 0; d < DD; ++d) whc[d * WCS + tid] = 0;
  }

  for (int L = 0; L < 2; ++L) {
    const float* W = L ? W1 : W0;
    const float* av = L ? a1 : a0;
    ushort* xg = L ? xg1 : xg0;

    for (int h = 0; h < HH; ++h) {
      // ---- stage wt[n][k] = W[k][h*32+n] (bf16, packed k-pairs) ----
      {
        const int n = tid & 31;
        const int p0 = (tid >> 5) * 8;
        #pragma unroll
        for (int p = 0; p < 8; ++p) {
          int k = (p0 + p) * 2;
          *(uint*)&wt[n * XK + k] =
              pk2(W[k * FF + h * DD + n], W[(k + 1) * FF + h * DD + n]);
        }
      }
      __syncthreads();  // wt ready; also guards whc/s1s/s2c overwrite vs prev PV

      // ---- GEMM: Whh[c][d] = xc[c][:] @ W_h, write transposed into whc[d][c] ----
      {
        bf16x8 bfr[2][4];
        #pragma unroll
        for (int ct = 0; ct < 2; ++ct)
          #pragma unroll
          for (int ks = 0; ks < 4; ++ks)
            bfr[ct][ks] = *(const bf16x8*)&wt[(ct * 16 + la) * XK + ks * 32 + lg * 8];
        for (int rt = w; rt < nrt; rt += 4) {
          f32x4 acc[2] = {};
          #pragma unroll
          for (int ks = 0; ks < 4; ++ks) {
            bf16x8 af = *(const bf16x8*)&xc[(rt * 16 + la) * XK + ks * 32 + lg * 8];
            acc[0] = __builtin_amdgcn_mfma_f32_16x16x32_bf16(af, bfr[0][ks], acc[0], 0, 0, 0);
            acc[1] = __builtin_amdgcn_mfma_f32_16x16x32_bf16(af, bfr[1][ks], acc[1], 0, 0, 0);
          }
          #pragma unroll
          for (int ct = 0; ct < 2; ++ct)
            #pragma unroll
            for (int reg = 0; reg < 4; ++reg)
              whc[(ct * 16 + la) * WCS + rt * 16 + lg * 4 + reg] = f2bfn(acc[ct][reg]);
        }
      }
      __syncthreads();

      // ---- scores per compact node c (scaled by log2 e) + block max of s2 ----
      {
        const int c = tid;
        float s1 = 0.f, s2 = 0.f;
        if (c < jv16) {
          #pragma unroll
          for (int d = 0; d < DD; ++d) {
            float wv = bf2f(whc[d * WCS + c]);
            s1 = fmaf(wv, av[d], s1);
            s2 = fmaf(wv, av[DD + d], s2);
          }
        }
        s1s[c] = s1 * L2E;
        bool vc = c < jv;
        s2c[c] = vc ? s2 * L2E : -2e9f;  // pad cols -> p = 0 exactly
        float m = vc ? s2 * L2E : -1e30f;
        #pragma unroll
        for (int off = 32; off > 0; off >>= 1) m = fmaxf(m, __shfl_xor(m, off));
        if (lane == 0) redm[w] = m;
      }
      __syncthreads();
      const float s2max = fmaxf(fmaxf(redm[0], redm[1]), fmaxf(redm[2], redm[3]));

      // ---- PV: P generated in registers (rank-1 scores), MFMA, fused epilogue ----
      for (int rt = w; rt < nrt; rt += 4) {
        const float s1v = s1s[rt * 16 + la];
        const float tt = s1v + s2max;
        const float em = fmaxf(tt, 0.2f * tt);  // exact row max (lrelu monotone)
        f32x4 acc[2] = {};
        float den = 0.f;
        for (int j0b = 0; j0b < jvp64; j0b += 64) {
          #pragma unroll
          for (int ks = 0; ks < 2; ++ks) {
            const int j0 = j0b + ks * 32 + lg * 8;
            float4 sa = *(const float4*)&s2c[j0];
            float4 sb = *(const float4*)&s2c[j0 + 4];
            bf16x8 b0 = *(const bf16x8*)&whc[la * WCS + j0];
            bf16x8 b1 = *(const bf16x8*)&whc[(16 + la) * WCS + j0];
            float t0 = s1v + sa.x, t1 = s1v + sa.y, t2 = s1v + sa.z, t3 = s1v + sa.w;
            float t4 = s1v + sb.x, t5 = s1v + sb.y, t6 = s1v + sb.z, t7 = s1v + sb.w;
            float p0 = exp2_fast(fmaxf(t0, 0.2f * t0) - em);
            float p1 = exp2_fast(fmaxf(t1, 0.2f * t1) - em);
            float p2 = exp2_fast(fmaxf(t2, 0.2f * t2) - em);
            float p3 = exp2_fast(fmaxf(t3, 0.2f * t3) - em);
            float p4 = exp2_fast(fmaxf(t4, 0.2f * t4) - em);
            float p5 = exp2_fast(fmaxf(t5, 0.2f * t5) - em);
            float p6 = exp2_fast(fmaxf(t6, 0.2f * t6) - em);
            float p7 = exp2_fast(fmaxf(t7, 0.2f * t7) - em);
            den += ((p0 + p1) + (p2 + p3)) + ((p4 + p5) + (p6 + p7));
            union { uint4 q; bf16x8 v; } u;
            u.q.x = pk2(p0, p1); u.q.y = pk2(p2, p3);
            u.q.z = pk2(p4, p5); u.q.w = pk2(p6, p7);
            acc[0] = __builtin_amdgcn_mfma_f32_16x16x32_bf16(u.v, b0, acc[0], 0, 0, 0);
            acc[1] = __builtin_amdgcn_mfma_f32_16x16x32_bf16(u.v, b1, acc[1], 0, 0, 0);
          }
        }
        den += __shfl_xor(den, 16);
        den += __shfl_xor(den, 32);
        const float inv = 1.f / den;  // every compact row has p_self > 0
        ushort* xgp = xg + (size_t)bt * NN * FF;
        #pragma unroll
        for (int reg = 0; reg < 4; ++reg) {
          const int c2 = rt * 16 + lg * 4 + reg;
          const float invr = __shfl(inv, lg * 4 + reg);
          #pragma unroll
          for (int nt = 0; nt < 2; ++nt) {
            const int f = h * DD + nt * 16 + la;
            float v = elu1(bf2f(xc[c2 * XK + f]) + acc[nt][reg] * invr);
            xgp[(size_t)c2 * FF + f] = f2bfn(v);
          }
        }
      }
      // next head's wt-stage barrier orders whc overwrite vs this PV
    }  // heads

    if (L == 0) {
      __syncthreads();  // drains vmcnt: xg0 writes visible via L2
      const int r0 = tid >> 4;
      const int c0 = (tid & 15) * 8;
      #pragma unroll
      for (int it = 0; it < 16; ++it) {
        int r = r0 + it * 16;
        if (r < jv)
          *(uint4*)&xc[r * XK + c0] =
              *(const uint4*)&xg0[((size_t)bt * NN + r) * FF + c0];
        // pad rows [jv, jv16) still zero from phase A
      }
    }
  }  // layers

  __syncthreads();  // xg1 writes drained/visible

  // ---- LN + scatter (zeros for invalid rows) ----
  {
    const int i = tid;
    const int rk2 = rrank[i];
    float* op = out + ((size_t)bt * NN + i) * FF;
    if (rk2 < 0) {
      float4 z = {0.f, 0.f, 0.f, 0.f};
      #pragma unroll
      for (int q = 0; q < 32; ++q) *(float4*)&op[q * 4] = z;
    } else {
      const ushort* xr = xg1 + ((size_t)bt * NN + rk2) * FF;
      float sum = 0.f, sq = 0.f;
      #pragma unroll
      for (int q = 0; q < 16; ++q) {
        uint4 u = *(const uint4*)&xr[q * 8];
        const uint* pu = (const uint*)&u;
        #pragma unroll
        for (int e = 0; e < 4; ++e) {
          float f0 = bf2f((ushort)(pu[e] & 0xffffu));
          float f1 = bf2f((ushort)(pu[e] >> 16));
          sum += f0 + f1;
          sq = fmaf(f0, f0, fmaf(f1, f1, sq));
        }
      }
      const float mu = sum * (1.f / FF);
      const float var = sq * (1.f / FF) - mu * mu;
      const float rstd = rsqrtf(var + 1e-5f);
      #pragma unroll
      for (int q = 0; q < 16; ++q) {
        uint4 u = *(const uint4*)&xr[q * 8];
        const uint* pu = (const uint*)&u;
        float4 o0, o1;
        float* po = (float*)&o0;
        #pragma unroll
        for (int e = 0; e < 4; ++e) {
          float f0 = bf2f((ushort)(pu[e] & 0xffffu));
          float f1 = bf2f((ushort)(pu[e] >> 16));
          ((e < 2) ? o0 : o1)[(e & 1) * 2]     = (f0 - mu) * rstd * gam[q * 8 + e * 2]     + bet[q * 8 + e * 2];
          ((e < 2) ? o0 : o1)[(e & 1) * 2 + 1] = (f1 - mu) * rstd * gam[q * 8 + e * 2 + 1] + bet[q * 8 + e * 2 + 1];
        }
        (void)po;
        *(float4*)&op[q * 8] = o0;
        *(float4*)&op[q * 8 + 4] = o1;
      }
    }
  }
}

extern "C" void kernel_launch(void* const* d_in, const int* in_sizes, int n_in,
                              void* d_out, int out_size, void* d_ws, size_t ws_size,
                              hipStream_t stream) {
  const float* xin   = (const float*)d_in[0];
  const int*   mask  = (const int*)d_in[1];
  const float* W0    = (const float*)d_in[2];
  const float* a0    = (const float*)d_in[3];
  const float* W1    = (const float*)d_in[4];
  const float* a1    = (const float*)d_in[5];
  const float* gamma = (const float*)d_in[6];
  const float* beta  = (const float*)d_in[7];

  ushort* xg0 = (ushort*)d_ws;                      // 8.39 MB (layer-0 xnew, bf16)
  ushort* xg1 = xg0 + (size_t)BT * NN * FF;         // 8.39 MB (layer-1 xnew, bf16)

  fused_gnn<<<BT, 256, 0, stream>>>(xin, mask, W0, a0, W1, a1, gamma, beta,
                                    xg0, xg1, (float*)d_out);
}

// Round 5
// 48.950 us; speedup vs baseline: 1.5338x; 1.5338x over previous
//
#include <hip/hip_runtime.h>
#include <hip/hip_bf16.h>

#define BT 128   // B*T
#define NN 256   // nodes
#define FF 128   // features
#define HH 4     // heads
#define DD 32    // head dim
#define XK 136   // LDS k-stride (bf16): 272B, 16B-aligned, spreads bank groups
#define WCS 264  // LDS col-stride (bf16) for whc: 528B
#define L2E 1.4426950408889634f

typedef __attribute__((ext_vector_type(8))) short bf16x8;
typedef __attribute__((ext_vector_type(4))) float f32x4;
typedef unsigned int uint;
typedef unsigned short ushort;

__device__ __forceinline__ float elu1(float x) { return x > 0.f ? x : (__expf(x) - 1.f); }
__device__ __forceinline__ float exp2_fast(float x) {
  float r; asm("v_exp_f32 %0, %1" : "=v"(r) : "v"(x)); return r;
}
__device__ __forceinline__ ushort f2bfn(float f) {
  __hip_bfloat16 h = __float2bfloat16(f);
  return *reinterpret_cast<ushort*>(&h);
}
__device__ __forceinline__ float bf2f(ushort u) {
  union { uint u; float f; } v; v.u = ((uint)u) << 16; return v.f;
}
__device__ __forceinline__ uint pk2(float a, float b) {  // -> v_cvt_pk_bf16_f32
  return (uint)f2bfn(a) | ((uint)f2bfn(b) << 16);
}

// Block = (bt, head). Ballot-compact valid nodes; stream x in 64-row chunks
// through LDS into a per-head GEMM (Whh^T built compacted in LDS, never global);
// rank-1 scores; register-generated P; PV MFMA; fused residual+ELU -> compact
// bf16 xg. L0: x from fp32 xin (gathered); L1: x from compact bf16 xprev.
template<bool L0>
__global__ __launch_bounds__(256) void layer_kernel(
    const float* __restrict__ xin, const ushort* __restrict__ xprev,
    const int* __restrict__ mask, const float* __restrict__ W,
    const float* __restrict__ av, ushort* __restrict__ xg,
    int* __restrict__ rrank_g) {
  __shared__ __align__(16) ushort xchunk[64 * XK];  // 17.4 KB
  __shared__ __align__(16) ushort wt[DD * XK];      // 8.7 KB
  __shared__ __align__(16) ushort whc[DD * WCS];    // 16.9 KB
  __shared__ __align__(16) float s1s[NN];
  __shared__ __align__(16) float s2c[NN];
  __shared__ int jmap[NN];
  __shared__ float redm[4];
  __shared__ int wcnt[4];

  const int bt = blockIdx.x >> 2;
  const int h = blockIdx.x & 3;
  const int tid = threadIdx.x;
  const int lane = tid & 63;
  const int w = tid >> 6;
  const int la = lane & 15, lg = lane >> 4;

  // ---- ballot compaction (mask is layer/head-invariant) ----
  const int mv = mask[bt * NN + tid] > 0;
  unsigned long long bal = __ballot(mv);
  if (lane == 0) wcnt[w] = __popcll(bal);
  __syncthreads();
  int base = 0;
  #pragma unroll
  for (int ww = 0; ww < 4; ++ww) if (ww < w) base += wcnt[ww];
  const int jv = wcnt[0] + wcnt[1] + wcnt[2] + wcnt[3];
  const int rk = mv ? base + __popcll(bal & ((1ull << lane) - 1ull)) : -1;
  if (mv) jmap[rk] = tid;
  if (L0 && h == 0) rrank_g[bt * NN + tid] = rk;

  const int jv16 = (jv + 15) & ~15;
  const int ntiles = jv16 >> 4;
  const int jvp64 = (jv16 + 63) & ~63;
  const int njb = jvp64 >> 6;

  // zero whc pad cols [jv16, jvp64): p=0 there, keep 0*0=0 (no NaN garbage)
  if (tid >= jv16 && tid < jvp64) {
    #pragma unroll
    for (int d = 0; d < DD; ++d) whc[d * WCS + tid] = 0;
  }
  // stage wt[n][k] = W[k][h*32+n] (bf16, packed k-pairs)
  {
    const int n = tid & 31;
    const int p0 = (tid >> 5) * 8;
    #pragma unroll
    for (int p = 0; p < 8; ++p) {
      int k = (p0 + p) * 2;
      *(uint*)&wt[n * XK + k] =
          pk2(W[k * FF + h * DD + n], W[(k + 1) * FF + h * DD + n]);
    }
  }
  __syncthreads();  // jmap, wt, whc-pads ready

  // preload B fragments (reused across all chunks)
  bf16x8 bfr[2][4];
  #pragma unroll
  for (int ct = 0; ct < 2; ++ct)
    #pragma unroll
    for (int ks = 0; ks < 4; ++ks)
      bfr[ct][ks] = *(const bf16x8*)&wt[(ct * 16 + la) * XK + ks * 32 + lg * 8];

  // ---- GEMM over compact rows, 64-row chunks, whc[d][c] transposed write ----
  for (int cb = 0; cb < jv16; cb += 64) {
    {
      const int r0 = tid >> 4;
      const int c0 = (tid & 15) * 8;
      #pragma unroll
      for (int it = 0; it < 4; ++it) {
        int r = r0 + it * 16;
        int g = cb + r;
        if (g < jv) {
          if (L0) {
            const float* xp = xin + ((size_t)bt * NN + jmap[g]) * FF + c0;
            float4 v0 = *(const float4*)xp;
            float4 v1 = *(const float4*)(xp + 4);
            uint4 qq;
            qq.x = pk2(v0.x, v0.y); qq.y = pk2(v0.z, v0.w);
            qq.z = pk2(v1.x, v1.y); qq.w = pk2(v1.z, v1.w);
            *(uint4*)&xchunk[r * XK + c0] = qq;
          } else {
            *(uint4*)&xchunk[r * XK + c0] =
                *(const uint4*)&xprev[((size_t)bt * NN + g) * FF + c0];
          }
        } else if (g < jv16) {
          uint4 z = {0, 0, 0, 0};
          *(uint4*)&xchunk[r * XK + c0] = z;
        }
      }
    }
    __syncthreads();  // xchunk ready (also: all PV reads of whc done before writes below)
    const int rows_in = min(64, jv16 - cb);
    if (w * 16 < rows_in) {
      f32x4 acc[2] = {};
      #pragma unroll
      for (int ks = 0; ks < 4; ++ks) {
        bf16x8 af = *(const bf16x8*)&xchunk[(w * 16 + la) * XK + ks * 32 + lg * 8];
        acc[0] = __builtin_amdgcn_mfma_f32_16x16x32_bf16(af, bfr[0][ks], acc[0], 0, 0, 0);
        acc[1] = __builtin_amdgcn_mfma_f32_16x16x32_bf16(af, bfr[1][ks], acc[1], 0, 0, 0);
      }
      #pragma unroll
      for (int ct = 0; ct < 2; ++ct)
        #pragma unroll
        for (int reg = 0; reg < 4; ++reg)
          whc[(ct * 16 + la) * WCS + cb + w * 16 + lg * 4 + reg] = f2bfn(acc[ct][reg]);
    }
    __syncthreads();  // whc chunk written before next chunk reuses xchunk
  }

  // ---- scores per compact node (scaled by log2 e) + block max of s2 ----
  {
    const int c = tid;
    float s1 = 0.f, s2 = 0.f;
    if (c < jv16) {
      #pragma unroll
      for (int d = 0; d < DD; ++d) {
        float wv = bf2f(whc[d * WCS + c]);
        s1 = fmaf(wv, av[d], s1);
        s2 = fmaf(wv, av[DD + d], s2);
      }
    }
    s1s[c] = s1 * L2E;
    bool vc = c < jv;
    s2c[c] = vc ? s2 * L2E : -2e9f;  // pad cols -> p = 0 exactly
    float m = vc ? s2 * L2E : -1e30f;
    #pragma unroll
    for (int off = 32; off > 0; off >>= 1) m = fmaxf(m, __shfl_xor(m, off));
    if (lane == 0) redm[w] = m;
  }
  __syncthreads();
  const float s2max = fmaxf(fmaxf(redm[0], redm[1]), fmaxf(redm[2], redm[3]));

  // ---- PV: wave w owns tiles ti = mi*4 + w; P generated in registers ----
  float s1r[4], em[4];
  #pragma unroll
  for (int mi = 0; mi < 4; ++mi) {
    float s1v = s1s[(mi * 4 + w) * 16 + la];
    s1r[mi] = s1v;
    float t = s1v + s2max;
    em[mi] = fmaxf(t, 0.2f * t);  // exact row max (lrelu monotone)
  }
  f32x4 acc[4][2] = {};
  float den[4] = {0.f, 0.f, 0.f, 0.f};
  for (int jb = 0; jb < njb; ++jb) {
    #pragma unroll
    for (int ks = 0; ks < 2; ++ks) {
      const int j0 = jb * 64 + ks * 32 + lg * 8;
      float4 sa = *(const float4*)&s2c[j0];
      float4 sb = *(const float4*)&s2c[j0 + 4];
      bf16x8 b0 = *(const bf16x8*)&whc[la * WCS + j0];
      bf16x8 b1 = *(const bf16x8*)&whc[(16 + la) * WCS + j0];
      #pragma unroll
      for (int mi = 0; mi < 4; ++mi) {
        if (mi * 4 + w < ntiles) {  // wave-uniform
          const float s1v = s1r[mi], emv = em[mi];
          float t0 = s1v + sa.x, t1 = s1v + sa.y, t2 = s1v + sa.z, t3 = s1v + sa.w;
          float t4 = s1v + sb.x, t5 = s1v + sb.y, t6 = s1v + sb.z, t7 = s1v + sb.w;
          float p0 = exp2_fast(fmaxf(t0, 0.2f * t0) - emv);
          float p1 = exp2_fast(fmaxf(t1, 0.2f * t1) - emv);
          float p2 = exp2_fast(fmaxf(t2, 0.2f * t2) - emv);
          float p3 = exp2_fast(fmaxf(t3, 0.2f * t3) - emv);
          float p4 = exp2_fast(fmaxf(t4, 0.2f * t4) - emv);
          float p5 = exp2_fast(fmaxf(t5, 0.2f * t5) - emv);
          float p6 = exp2_fast(fmaxf(t6, 0.2f * t6) - emv);
          float p7 = exp2_fast(fmaxf(t7, 0.2f * t7) - emv);
          den[mi] += ((p0 + p1) + (p2 + p3)) + ((p4 + p5) + (p6 + p7));
          union { uint4 q; bf16x8 v; } u;
          u.q.x = pk2(p0, p1); u.q.y = pk2(p2, p3);
          u.q.z = pk2(p4, p5); u.q.w = pk2(p6, p7);
          acc[mi][0] = __builtin_amdgcn_mfma_f32_16x16x32_bf16(u.v, b0, acc[mi][0], 0, 0, 0);
          acc[mi][1] = __builtin_amdgcn_mfma_f32_16x16x32_bf16(u.v, b1, acc[mi][1], 0, 0, 0);
        }
      }
    }
  }
  #pragma unroll
  for (int mi = 0; mi < 4; ++mi) {
    den[mi] += __shfl_xor(den[mi], 16);
    den[mi] += __shfl_xor(den[mi], 32);
  }

  // ---- epilogue: residual + ELU -> compact bf16 xg ----
  #pragma unroll
  for (int mi = 0; mi < 4; ++mi) {
    const int ti = mi * 4 + w;
    if (ti < ntiles) {
      const float inv = 1.f / den[mi];  // every valid row has p_self > 0
      #pragma unroll
      for (int reg = 0; reg < 4; ++reg) {
        const float invr = __shfl(inv, lg * 4 + reg);  // full-wave participation
        const int c2 = ti * 16 + lg * 4 + reg;
        if (c2 < jv) {
          #pragma unroll
          for (int nt = 0; nt < 2; ++nt) {
            const int f = h * DD + nt * 16 + la;
            float resid;
            if (L0) resid = xin[((size_t)bt * NN + jmap[c2]) * FF + f];
            else    resid = bf2f(xprev[((size_t)bt * NN + c2) * FF + f]);
            float v = elu1(resid + acc[mi][nt][reg] * invr);
            xg[((size_t)bt * NN + c2) * FF + f] = f2bfn(v);
          }
        }
      }
    }
  }
}

// Block = (bt, node-quarter). 4 lanes per node row (32 features each);
// LN stats combined via shfl within the 4-lane group; scatter + zero-fill.
__global__ __launch_bounds__(256) void ln_scatter(
    const ushort* __restrict__ xg1, const int* __restrict__ rrank_g,
    const float* __restrict__ gam, const float* __restrict__ bet,
    float* __restrict__ out) {
  const int bt = blockIdx.x >> 2;
  const int q = blockIdx.x & 3;
  const int node = q * 64 + (threadIdx.x >> 2);
  const int fb = (threadIdx.x & 3) * 32;
  const int rk = rrank_g[bt * NN + node];  // same for all 4 lanes of the group
  float* op = out + ((size_t)bt * NN + node) * FF + fb;
  if (rk < 0) {
    float4 z = {0.f, 0.f, 0.f, 0.f};
    #pragma unroll
    for (int i = 0; i < 8; ++i) *(float4*)&op[i * 4] = z;
  } else {
    const ushort* xr = xg1 + ((size_t)bt * NN + rk) * FF + fb;
    float f[32];
    #pragma unroll
    for (int i = 0; i < 4; ++i) {
      uint4 u = *(const uint4*)&xr[i * 8];
      const uint* pu = (const uint*)&u;
      #pragma unroll
      for (int e = 0; e < 4; ++e) {
        f[i * 8 + e * 2]     = bf2f((ushort)(pu[e] & 0xffffu));
        f[i * 8 + e * 2 + 1] = bf2f((ushort)(pu[e] >> 16));
      }
    }
    float sum = 0.f, sq = 0.f;
    #pragma unroll
    for (int i = 0; i < 32; ++i) { sum += f[i]; sq = fmaf(f[i], f[i], sq); }
    sum += __shfl_xor(sum, 1); sq += __shfl_xor(sq, 1);
    sum += __shfl_xor(sum, 2); sq += __shfl_xor(sq, 2);
    const float mu = sum * (1.f / FF);
    const float var = sq * (1.f / FF) - mu * mu;
    const float rstd = rsqrtf(var + 1e-5f);
    #pragma unroll
    for (int i = 0; i < 8; ++i) {
      float4 g = *(const float4*)&gam[fb + i * 4];
      float4 b = *(const float4*)&bet[fb + i * 4];
      float4 o;
      o.x = (f[i * 4]     - mu) * rstd * g.x + b.x;
      o.y = (f[i * 4 + 1] - mu) * rstd * g.y + b.y;
      o.z = (f[i * 4 + 2] - mu) * rstd * g.z + b.z;
      o.w = (f[i * 4 + 3] - mu) * rstd * g.w + b.w;
      *(float4*)&op[i * 4] = o;
    }
  }
}

extern "C" void kernel_launch(void* const* d_in, const int* in_sizes, int n_in,
                              void* d_out, int out_size, void* d_ws, size_t ws_size,
                              hipStream_t stream) {
  const float* xin   = (const float*)d_in[0];
  const int*   mask  = (const int*)d_in[1];
  const float* W0    = (const float*)d_in[2];
  const float* a0    = (const float*)d_in[3];
  const float* W1    = (const float*)d_in[4];
  const float* a1    = (const float*)d_in[5];
  const float* gamma = (const float*)d_in[6];
  const float* beta  = (const float*)d_in[7];

  ushort* xg0     = (ushort*)d_ws;                   // 8.39 MB compact bf16
  ushort* xg1     = xg0 + (size_t)BT * NN * FF;      // 8.39 MB compact bf16
  int*    rrank_g = (int*)(xg1 + (size_t)BT * NN * FF);  // 131 KB

  layer_kernel<true><<<BT * HH, 256, 0, stream>>>(xin, nullptr, mask, W0, a0, xg0, rrank_g);
  layer_kernel<false><<<BT * HH, 256, 0, stream>>>(nullptr, xg0, mask, W1, a1, xg1, nullptr);
  ln_scatter<<<BT * 4, 256, 0, stream>>>(xg1, rrank_g, gamma, beta, (float*)d_out);
}